// Round 2
// 425.725 us; speedup vs baseline: 1.0354x; 1.0354x over previous
//
#include <hip/hip_runtime.h>
#include <cstdint>

#define VOCAB  50257
#define BSZ    128
#define KD     8
#define NDRAFT (BSZ * KD)
#define SEG    16
#define SEGLEN 3142   // ceil(VOCAB/SEG) for the bonus scalar segmentation

typedef float fx4 __attribute__((ext_vector_type(4)));

__device__ inline fx4 ntload4(const fx4* p) {
  return __builtin_nontemporal_load(p);
}

// ---------------- JAX threefry2x32 (exact) ----------------
__host__ __device__ inline uint32_t rotl32(uint32_t x, int r) {
  return (x << r) | (x >> (32 - r));
}

__host__ __device__ inline void threefry2x32(uint32_t k0, uint32_t k1,
                                             uint32_t x0, uint32_t x1,
                                             uint32_t& o0, uint32_t& o1) {
  uint32_t ks2 = k0 ^ k1 ^ 0x1BD11BDAu;
  x0 += k0; x1 += k1;
  x0 += x1; x1 = rotl32(x1, 13); x1 ^= x0;
  x0 += x1; x1 = rotl32(x1, 15); x1 ^= x0;
  x0 += x1; x1 = rotl32(x1, 26); x1 ^= x0;
  x0 += x1; x1 = rotl32(x1,  6); x1 ^= x0;
  x0 += k1; x1 += ks2 + 1u;
  x0 += x1; x1 = rotl32(x1, 17); x1 ^= x0;
  x0 += x1; x1 = rotl32(x1, 29); x1 ^= x0;
  x0 += x1; x1 = rotl32(x1, 16); x1 ^= x0;
  x0 += x1; x1 = rotl32(x1, 24); x1 ^= x0;
  x0 += ks2; x1 += k0 + 2u;
  x0 += x1; x1 = rotl32(x1, 13); x1 ^= x0;
  x0 += x1; x1 = rotl32(x1, 15); x1 ^= x0;
  x0 += x1; x1 = rotl32(x1, 26); x1 ^= x0;
  x0 += x1; x1 = rotl32(x1,  6); x1 ^= x0;
  x0 += k0; x1 += k1 + 3u;
  x0 += x1; x1 = rotl32(x1, 17); x1 ^= x0;
  x0 += x1; x1 = rotl32(x1, 29); x1 ^= x0;
  x0 += x1; x1 = rotl32(x1, 16); x1 ^= x0;
  x0 += x1; x1 = rotl32(x1, 24); x1 ^= x0;
  x0 += k1; x1 += ks2 + 4u;
  x0 += x1; x1 = rotl32(x1, 13); x1 ^= x0;
  x0 += x1; x1 = rotl32(x1, 15); x1 ^= x0;
  x0 += x1; x1 = rotl32(x1, 26); x1 ^= x0;
  x0 += x1; x1 = rotl32(x1,  6); x1 ^= x0;
  x0 += ks2; x1 += k0 + 5u;
  o0 = x0; o1 = x1;
}

// jax_threefry_partitionable=True: bits(i) = o0^o1 of threefry(key, hi32(i), lo32(i))
__device__ inline uint32_t tf_bits32(uint32_t k0, uint32_t k1, uint64_t idx) {
  uint32_t o0, o1;
  threefry2x32(k0, k1, (uint32_t)(idx >> 32), (uint32_t)idx, o0, o1);
  return o0 ^ o1;
}

__device__ inline float bits_to_f01(uint32_t bits) {
  return __uint_as_float((bits >> 9) | 0x3f800000u) - 1.0f;
}

// fast-intrinsic gumbel (v_log_f32-based); ~1e-6 abs error vs libm
__device__ inline float gumbel_fast(uint32_t bits) {
  const float tiny = 1.1754943508222875e-38f;
  float u = fmaxf(tiny, bits_to_f01(bits) + tiny);
  return -__logf(-__logf(u));
}

// order-preserving (score, idx) pack; ties -> smallest idx wins under max
__device__ inline unsigned long long pack_si(float s, int idx) {
  uint32_t u = __float_as_uint(s);
  u = (u & 0x80000000u) ? ~u : (u | 0x80000000u);
  return ((unsigned long long)u << 32) | (uint32_t)(VOCAB - idx);
}
__device__ inline int unpack_idx(unsigned long long p) {
  return VOCAB - (int)(p & 0xFFFFFFFFu);
}

// leading-accept count from per-b bitmask (bit j = position j accepted)
__device__ inline int nacc_from_bits(int bits) {
  return __builtin_ctz(~bits & 0x1FF);   // bit 8 of ~bits always set -> result in [0,8]
}

// ---- Kernel A: fused one-pass softmax stats + accept decision (blocks 0..NDRAFT-1)
//                + bonus gumbel-argmax partials (blocks NDRAFT..NDRAFT+BSZ*SEG-1)
__global__ __launch_bounds__(256) void k_stats_bonus(
    const float* __restrict__ logits, const float* __restrict__ temps,
    const int* __restrict__ dtok, const float* __restrict__ dprobs,
    float* __restrict__ row_max, float* __restrict__ row_sum,
    int* __restrict__ acc_bits,
    unsigned long long* __restrict__ bon_pack,
    uint32_t kb0, uint32_t kb1, uint32_t ku0, uint32_t ku1) {
  int tid = threadIdx.x;
  if ((int)blockIdx.x < NDRAFT) {
    // ---------- one-pass online softmax over row + fused accept ----------
    int row = blockIdx.x;
    int b = row >> 3;
    float t = temps[b];
    float inv_t = 1.0f / t;
    const float* x = logits + (size_t)row * VOCAB;

    // issue the two accept-gather loads early; latency hides under the stream
    int tok = 0; float x_tok = 0.0f, pd_tok = 0.0f;
    if (tid == 0) {
      tok    = dtok[row];
      x_tok  = x[tok];
      pd_tok = dprobs[(size_t)row * VOCAB + tok];
    }

    float m_t = -INFINITY, s_t = 0.0f;
    auto upd = [&](float val) {
      float xs = val * inv_t;
      float nm = fmaxf(m_t, xs);
      s_t = s_t * __expf(m_t - nm) + __expf(xs - nm);
      m_t = nm;
    };
    // row base elem offset = row*50257 ≡ row (mod 4) -> alignment prologue
    int pre = (4 - (row & 3)) & 3;
    if (tid < pre) upd(x[tid]);
    int nv = (VOCAB - pre) >> 2;
    const fx4* xv = (const fx4*)(x + pre);
    // 2x pairing: keeps >=2 loads in flight; per-thread accumulation order is
    // IDENTICAL to the plain stride-256 loop (numerics bit-exact).
    int i = tid;
    for (; i + 256 < nv; i += 512) {
      fx4 q0 = ntload4(xv + i);
      fx4 q1 = ntload4(xv + i + 256);
      upd(q0.x); upd(q0.y); upd(q0.z); upd(q0.w);
      upd(q1.x); upd(q1.y); upd(q1.z); upd(q1.w);
    }
    for (; i < nv; i += 256) {
      fx4 q = ntload4(xv + i);
      upd(q.x); upd(q.y); upd(q.z); upd(q.w);
    }
    for (int v = pre + 4 * nv + tid; v < VOCAB; v += 256) upd(x[v]);

    __shared__ float sm[256], ss[256];
    sm[tid] = m_t; ss[tid] = s_t;
    __syncthreads();
    for (int st = 128; st > 0; st >>= 1) {
      if (tid < st) {
        float m2 = sm[tid + st], s2 = ss[tid + st];
        float M = fmaxf(sm[tid], m2);
        ss[tid] = ss[tid] * __expf(sm[tid] - M) + s2 * __expf(m2 - M);
        sm[tid] = M;
      }
      __syncthreads();
    }
    if (tid == 0) {
      float M = sm[0], S = ss[0];
      row_max[row] = M; row_sum[row] = S;
      // accept decision — numerically identical to the former k_accept
      float xt = x_tok / t;
      float pt = expf(xt - M) / S;
      float ap = (pd_tok > 0.0f) ? fminf(1.0f, pt / fmaxf(pd_tok, 1e-30f)) : 0.0f;
      float u  = bits_to_f01(tf_bits32(ku0, ku1, (uint64_t)row));
      if (u <= ap) atomicOr(&acc_bits[b], 1 << (row & 7));
    }
  } else {
    // ---------- bonus segment: argmax(logits/t + gumbel) ----------
    int r = blockIdx.x - NDRAFT;
    int b = r >> 4, seg = r & 15;
    int v0 = seg * SEGLEN;
    int v1 = v0 + SEGLEN; if (v1 > VOCAB) v1 = VOCAB;
    float inv_t = 1.0f / temps[b];
    const float* x = logits + (size_t)(NDRAFT + b) * VOCAB;
    uint64_t base = (uint64_t)b * VOCAB;
    float bv = -INFINITY; int bi = VOCAB;
    for (int v = v0 + tid; v < v1; v += 256) {
      float sc = x[v] * inv_t + gumbel_fast(tf_bits32(kb0, kb1, base + v));
      if (sc > bv) { bv = sc; bi = v; }
    }
    __shared__ unsigned long long sp[256];
    sp[tid] = pack_si(bv, bi);
    __syncthreads();
    for (int st = 128; st > 0; st >>= 1) {
      if (tid < st) { if (sp[tid + st] > sp[tid]) sp[tid] = sp[tid + st]; }
      __syncthreads();
    }
    if (tid == 0) atomicMax(&bon_pack[b], sp[0]);
  }
}

// ---- Kernel C: recovery segments (capped + plain argmax, any-flag) ----
__global__ __launch_bounds__(256) void k_recover(
    const float* __restrict__ logits, const float* __restrict__ temps,
    const float* __restrict__ dprobs,
    const float* __restrict__ row_max, const float* __restrict__ row_sum,
    const int* __restrict__ acc_bits,
    unsigned long long* __restrict__ rec_pc,
    unsigned long long* __restrict__ rec_pp,
    int* __restrict__ rec_any,
    uint32_t kr0, uint32_t kr1) {
  int r = blockIdx.x;
  int b = r >> 4, seg = r & 15;
  int n = nacc_from_bits(acc_bits[b]);
  if (n >= KD) return;                 // all accepted: recovery unused
  int tid = threadIdx.x;
  int row = b * KD + n;                // rej_pos = min(n, KD-1) = n here
  float inv_t = 1.0f / temps[b];
  float m = row_max[row];
  float inv_s = 1.0f / row_sum[row];
  const float* x  = logits + (size_t)row * VOCAB;
  const float* pd = dprobs + (size_t)row * VOCAB;
  uint64_t base = (uint64_t)row * VOCAB;

  float bc = -INFINITY, bp = -INFINITY;
  int ic = VOCAB, ip = VOCAB, any = 0;

  auto proc = [&](float xval, float pdval, int v) {
    float pt = __expf(xval * inv_t - m) * inv_s;
    float diff = pt - pdval;
    if (diff > 0.0f) any = 1;
    float g = gumbel_fast(tf_bits32(kr0, kr1, base + (uint64_t)v));
    float scc = __logf(fmaxf(fmaxf(diff, 0.0f), 1e-30f)) + g;
    float scp = __logf(fmaxf(pt, 1e-30f)) + g;
    if (scc > bc) { bc = scc; ic = v; }
    if (scp > bp) { bp = scp; ip = v; }
  };

  // vectorized: argmax is order-independent; pack tie-break is deterministic
  int pre = (4 - (row & 3)) & 3;
  int nv = (VOCAB - pre) >> 2;
  const fx4* xv = (const fx4*)(x + pre);
  const fx4* pv = (const fx4*)(pd + pre);
  int per = (nv + SEG - 1) / SEG;
  int s0 = seg * per;
  int s1 = s0 + per; if (s1 > nv) s1 = nv;
  for (int i = s0 + tid; i < s1; i += 256) {
    fx4 qx = ntload4(xv + i);
    fx4 qp = ntload4(pv + i);
    int v = pre + 4 * i;
    proc(qx.x, qp.x, v);
    proc(qx.y, qp.y, v + 1);
    proc(qx.z, qp.z, v + 2);
    proc(qx.w, qp.w, v + 3);
  }
  if (seg == 0) {
    if (tid < pre) proc(x[tid], pd[tid], tid);
  }
  if (seg == SEG - 1) {
    for (int v = pre + 4 * nv + tid; v < VOCAB; v += 256) proc(x[v], pd[v], v);
  }

  __shared__ unsigned long long sp[256];
  __shared__ int sa[256];
  sp[tid] = pack_si(bc, ic); sa[tid] = any;
  __syncthreads();
  for (int st = 128; st > 0; st >>= 1) {
    if (tid < st) {
      if (sp[tid + st] > sp[tid]) sp[tid] = sp[tid + st];
      sa[tid] |= sa[tid + st];
    }
    __syncthreads();
  }
  if (tid == 0) {
    atomicMax(&rec_pc[b], sp[0]);
    if (sa[0]) atomicOr(&rec_any[b], 1);
  }
  __syncthreads();
  sp[tid] = pack_si(bp, ip);
  __syncthreads();
  for (int st = 128; st > 0; st >>= 1) {
    if (tid < st) { if (sp[tid + st] > sp[tid]) sp[tid] = sp[tid + st]; }
    __syncthreads();
  }
  if (tid == 0) atomicMax(&rec_pp[b], sp[0]);
}

// ---- Kernel D: assemble [bs, k+1] output ----
__global__ void k_final(const int* __restrict__ dtok,
                        const int* __restrict__ acc_bits,
                        const unsigned long long* __restrict__ bon_pack,
                        const unsigned long long* __restrict__ rec_pc,
                        const unsigned long long* __restrict__ rec_pp,
                        const int* __restrict__ rec_any,
                        int* __restrict__ out) {
  int idx = blockIdx.x * blockDim.x + threadIdx.x;
  if (idx >= BSZ * (KD + 1)) return;
  int b = idx / (KD + 1), p = idx % (KD + 1);
  int n = nacc_from_bits(acc_bits[b]);
  int val;
  if (p < n)       val = dtok[b * KD + p];
  else if (p == n) {
    if (n == KD) val = unpack_idx(bon_pack[b]);
    else         val = unpack_idx(rec_any[b] ? rec_pc[b] : rec_pp[b]);
  }
  else             val = -1;
  out[idx] = val;
}

extern "C" void kernel_launch(void* const* d_in, const int* in_sizes, int n_in,
                              void* d_out, int out_size, void* d_ws, size_t ws_size,
                              hipStream_t stream) {
  const int*   dtok   = (const int*)  d_in[0];
  const float* logits = (const float*)d_in[1];
  const float* temps  = (const float*)d_in[2];
  const float* dprobs = (const float*)d_in[3];
  int* out = (int*)d_out;

  unsigned long long* bon_pack = (unsigned long long*)d_ws;   // [BSZ]
  unsigned long long* rec_pc   = bon_pack + BSZ;              // [BSZ]
  unsigned long long* rec_pp   = rec_pc + BSZ;                // [BSZ]
  int*   rec_any  = (int*)(rec_pp + BSZ);                     // [BSZ]
  int*   acc_bits = rec_any + BSZ;                            // [BSZ]
  float* row_max  = (float*)(acc_bits + BSZ);                 // [NDRAFT]
  float* row_sum  = row_max + NDRAFT;                         // [NDRAFT]

  // nkey = key(42); split(nkey,3): subkey_i = threefry(key, (0,i))
  uint32_t ku0, ku1, kr0, kr1, kb0, kb1;
  threefry2x32(0u, 42u, 0u, 0u, ku0, ku1);   // ku       (accept uniforms)
  threefry2x32(0u, 42u, 0u, 1u, kr0, kr1);   // kg_rec   (recovery gumbel)
  threefry2x32(0u, 42u, 0u, 2u, kb0, kb1);   // kg_bonus (bonus gumbel)

  // zero the atomic destinations: bon_pack/rec_pc/rec_pp (packed -inf < 0),
  // rec_any, acc_bits  ->  3*BSZ*8 + 2*BSZ*4 = 4096 bytes
  hipMemsetAsync(d_ws, 0, (size_t)(3 * BSZ * 8 + 2 * BSZ * 4), stream);

  k_stats_bonus<<<NDRAFT + BSZ * SEG, 256, 0, stream>>>(
      logits, temps, dtok, dprobs, row_max, row_sum, acc_bits, bon_pack,
      kb0, kb1, ku0, ku1);
  k_recover<<<BSZ * SEG, 256, 0, stream>>>(logits, temps, dprobs,
                                           row_max, row_sum, acc_bits,
                                           rec_pc, rec_pp, rec_any, kr0, kr1);
  k_final<<<(BSZ * (KD + 1) + 255) / 256, 256, 0, stream>>>(
      dtok, acc_bits, bon_pack, rec_pc, rec_pp, rec_any, out);
}

// Round 3
// 412.635 us; speedup vs baseline: 1.0683x; 1.0317x over previous
//
#include <hip/hip_runtime.h>
#include <cstdint>

#define VOCAB  50257
#define BSZ    128
#define KD     8
#define NDRAFT (BSZ * KD)
#define SEG    16
#define SEGLEN 3142   // ceil(VOCAB/SEG) for the bonus scalar segmentation

typedef float fx4 __attribute__((ext_vector_type(4)));

__device__ inline fx4 ntload4(const fx4* p) {
  return __builtin_nontemporal_load(p);
}

// ---------------- JAX threefry2x32 (exact) ----------------
__host__ __device__ inline uint32_t rotl32(uint32_t x, int r) {
  return (x << r) | (x >> (32 - r));
}

__host__ __device__ inline void threefry2x32(uint32_t k0, uint32_t k1,
                                             uint32_t x0, uint32_t x1,
                                             uint32_t& o0, uint32_t& o1) {
  uint32_t ks2 = k0 ^ k1 ^ 0x1BD11BDAu;
  x0 += k0; x1 += k1;
  x0 += x1; x1 = rotl32(x1, 13); x1 ^= x0;
  x0 += x1; x1 = rotl32(x1, 15); x1 ^= x0;
  x0 += x1; x1 = rotl32(x1, 26); x1 ^= x0;
  x0 += x1; x1 = rotl32(x1,  6); x1 ^= x0;
  x0 += k1; x1 += ks2 + 1u;
  x0 += x1; x1 = rotl32(x1, 17); x1 ^= x0;
  x0 += x1; x1 = rotl32(x1, 29); x1 ^= x0;
  x0 += x1; x1 = rotl32(x1, 16); x1 ^= x0;
  x0 += x1; x1 = rotl32(x1, 24); x1 ^= x0;
  x0 += ks2; x1 += k0 + 2u;
  x0 += x1; x1 = rotl32(x1, 13); x1 ^= x0;
  x0 += x1; x1 = rotl32(x1, 15); x1 ^= x0;
  x0 += x1; x1 = rotl32(x1, 26); x1 ^= x0;
  x0 += x1; x1 = rotl32(x1,  6); x1 ^= x0;
  x0 += k0; x1 += k1 + 3u;
  x0 += x1; x1 = rotl32(x1, 17); x1 ^= x0;
  x0 += x1; x1 = rotl32(x1, 29); x1 ^= x0;
  x0 += x1; x1 = rotl32(x1, 16); x1 ^= x0;
  x0 += x1; x1 = rotl32(x1, 24); x1 ^= x0;
  x0 += k1; x1 += ks2 + 4u;
  x0 += x1; x1 = rotl32(x1, 13); x1 ^= x0;
  x0 += x1; x1 = rotl32(x1, 15); x1 ^= x0;
  x0 += x1; x1 = rotl32(x1, 26); x1 ^= x0;
  x0 += x1; x1 = rotl32(x1,  6); x1 ^= x0;
  x0 += ks2; x1 += k0 + 5u;
  o0 = x0; o1 = x1;
}

// jax_threefry_partitionable=True: bits(i) = o0^o1 of threefry(key, hi32(i), lo32(i))
__device__ inline uint32_t tf_bits32(uint32_t k0, uint32_t k1, uint64_t idx) {
  uint32_t o0, o1;
  threefry2x32(k0, k1, (uint32_t)(idx >> 32), (uint32_t)idx, o0, o1);
  return o0 ^ o1;
}

__device__ inline float bits_to_f01(uint32_t bits) {
  return __uint_as_float((bits >> 9) | 0x3f800000u) - 1.0f;
}

// fast-intrinsic gumbel (v_log_f32-based); ~1e-6 abs error vs libm
__device__ inline float gumbel_fast(uint32_t bits) {
  const float tiny = 1.1754943508222875e-38f;
  float u = fmaxf(tiny, bits_to_f01(bits) + tiny);
  return -__logf(-__logf(u));
}

// order-preserving (score, idx) pack; ties -> smallest idx wins under max
__device__ inline unsigned long long pack_si(float s, int idx) {
  uint32_t u = __float_as_uint(s);
  u = (u & 0x80000000u) ? ~u : (u | 0x80000000u);
  return ((unsigned long long)u << 32) | (uint32_t)(VOCAB - idx);
}
__device__ inline int unpack_idx(unsigned long long p) {
  return VOCAB - (int)(p & 0xFFFFFFFFu);
}

// leading-accept count from per-row flags (flag[j] = position j accepted)
__device__ inline int nacc_flags(const int* __restrict__ f, int b) {
  int n = 0;
#pragma unroll
  for (int j = 0; j < KD; j++) {
    if (f[b * KD + j]) n++;
    else break;
  }
  return n;
}

// ---- Kernel 1: one-pass softmax stats + accept decision (one block per draft row)
__global__ __launch_bounds__(256) void k_stats(
    const float* __restrict__ logits, const float* __restrict__ temps,
    const int* __restrict__ dtok, const float* __restrict__ dprobs,
    float* __restrict__ row_max, float* __restrict__ row_sum,
    int* __restrict__ acc_flag,
    uint32_t ku0, uint32_t ku1) {
  int tid = threadIdx.x;
  int row = blockIdx.x;
  int b = row >> 3;
  float t = temps[b];
  float inv_t = 1.0f / t;
  const float* x = logits + (size_t)row * VOCAB;

  // issue the two accept-gather loads early; latency hides under the stream
  int tok = 0; float x_tok = 0.0f, pd_tok = 0.0f;
  if (tid == 0) {
    tok    = dtok[row];
    x_tok  = x[tok];
    pd_tok = dprobs[(size_t)row * VOCAB + tok];
  }

  float m_t = -INFINITY, s_t = 0.0f;
  auto upd = [&](float val) {
    float xs = val * inv_t;
    float nm = fmaxf(m_t, xs);
    s_t = s_t * __expf(m_t - nm) + __expf(xs - nm);
    m_t = nm;
  };
  // row base elem offset = row*50257 ≡ row (mod 4) -> alignment prologue
  int pre = (4 - (row & 3)) & 3;
  if (tid < pre) upd(x[tid]);
  int nv = (VOCAB - pre) >> 2;
  const fx4* xv = (const fx4*)(x + pre);
  // 4-deep load pipeline; per-thread accumulation order is IDENTICAL to the
  // plain stride-256 loop (j, j+1, j+2, j+3 consumed in order) -> bit-exact.
  int i = tid;
  for (; i + 768 < nv; i += 1024) {
    fx4 q0 = ntload4(xv + i);
    fx4 q1 = ntload4(xv + i + 256);
    fx4 q2 = ntload4(xv + i + 512);
    fx4 q3 = ntload4(xv + i + 768);
    upd(q0.x); upd(q0.y); upd(q0.z); upd(q0.w);
    upd(q1.x); upd(q1.y); upd(q1.z); upd(q1.w);
    upd(q2.x); upd(q2.y); upd(q2.z); upd(q2.w);
    upd(q3.x); upd(q3.y); upd(q3.z); upd(q3.w);
  }
  for (; i < nv; i += 256) {
    fx4 q = ntload4(xv + i);
    upd(q.x); upd(q.y); upd(q.z); upd(q.w);
  }
  for (int v = pre + 4 * nv + tid; v < VOCAB; v += 256) upd(x[v]);

  __shared__ float sm[256], ss[256];
  sm[tid] = m_t; ss[tid] = s_t;
  __syncthreads();
  for (int st = 128; st > 0; st >>= 1) {
    if (tid < st) {
      float m2 = sm[tid + st], s2 = ss[tid + st];
      float M = fmaxf(sm[tid], m2);
      ss[tid] = ss[tid] * __expf(sm[tid] - M) + s2 * __expf(m2 - M);
      sm[tid] = M;
    }
    __syncthreads();
  }
  if (tid == 0) {
    float M = sm[0], S = ss[0];
    row_max[row] = M; row_sum[row] = S;
    // accept decision — numerically identical to the original k_accept
    float xt = x_tok / t;
    float pt = expf(xt - M) / S;
    float ap = (pd_tok > 0.0f) ? fminf(1.0f, pt / fmaxf(pd_tok, 1e-30f)) : 0.0f;
    float u  = bits_to_f01(tf_bits32(ku0, ku1, (uint64_t)row));
    acc_flag[row] = (u <= ap) ? 1 : 0;
  }
}

// ---- Kernel 2: bonus (gated on n_acc==KD) + recovery (gated on n_acc<KD)
//      blocks [0, BSZ*SEG)          : bonus segments
//      blocks [BSZ*SEG, 2*BSZ*SEG)  : recovery segments
//      No atomics: each (b,seg) writes its own partial slot.
__global__ __launch_bounds__(256) void k_bonus_recover(
    const float* __restrict__ logits, const float* __restrict__ temps,
    const float* __restrict__ dprobs,
    const float* __restrict__ row_max, const float* __restrict__ row_sum,
    const int* __restrict__ acc_flag,
    unsigned long long* __restrict__ bon_part,
    unsigned long long* __restrict__ rec_pc_part,
    unsigned long long* __restrict__ rec_pp_part,
    int* __restrict__ rec_any_part,
    uint32_t kb0, uint32_t kb1, uint32_t kr0, uint32_t kr1) {
  int tid = threadIdx.x;
  if ((int)blockIdx.x < BSZ * SEG) {
    // ---------- bonus segment: argmax(logits/t + gumbel), only if all accepted
    int r = blockIdx.x;
    int b = r >> 4, seg = r & 15;
    if (nacc_flags(acc_flag, b) != KD) return;   // bonus token unused
    int v0 = seg * SEGLEN;
    int v1 = v0 + SEGLEN; if (v1 > VOCAB) v1 = VOCAB;
    float inv_t = 1.0f / temps[b];
    const float* x = logits + (size_t)(NDRAFT + b) * VOCAB;
    uint64_t base = (uint64_t)b * VOCAB;
    float bv = -INFINITY; int bi = VOCAB;
    for (int v = v0 + tid; v < v1; v += 256) {
      float sc = x[v] * inv_t + gumbel_fast(tf_bits32(kb0, kb1, base + v));
      if (sc > bv) { bv = sc; bi = v; }
    }
    __shared__ unsigned long long sp[256];
    sp[tid] = pack_si(bv, bi);
    __syncthreads();
    for (int st = 128; st > 0; st >>= 1) {
      if (tid < st) { if (sp[tid + st] > sp[tid]) sp[tid] = sp[tid + st]; }
      __syncthreads();
    }
    if (tid == 0) bon_part[r] = sp[0];
  } else {
    // ---------- recovery segment: capped + plain argmax, any-flag ----------
    int r = blockIdx.x - BSZ * SEG;
    int b = r >> 4, seg = r & 15;
    int n = nacc_flags(acc_flag, b);
    if (n >= KD) return;                 // all accepted: recovery unused
    int row = b * KD + n;                // rej_pos = min(n, KD-1) = n here
    float inv_t = 1.0f / temps[b];
    float m = row_max[row];
    float inv_s = 1.0f / row_sum[row];
    const float* x  = logits + (size_t)row * VOCAB;
    const float* pd = dprobs + (size_t)row * VOCAB;
    uint64_t base = (uint64_t)row * VOCAB;

    float bc = -INFINITY, bp = -INFINITY;
    int ic = VOCAB, ip = VOCAB, any = 0;

    auto proc = [&](float xval, float pdval, int v) {
      float pt = __expf(xval * inv_t - m) * inv_s;
      float diff = pt - pdval;
      if (diff > 0.0f) any = 1;
      float g = gumbel_fast(tf_bits32(kr0, kr1, base + (uint64_t)v));
      float scc = __logf(fmaxf(fmaxf(diff, 0.0f), 1e-30f)) + g;
      float scp = __logf(fmaxf(pt, 1e-30f)) + g;
      if (scc > bc) { bc = scc; ic = v; }
      if (scp > bp) { bp = scp; ip = v; }
    };

    // vectorized: argmax is order-independent; pack tie-break is deterministic
    int pre = (4 - (row & 3)) & 3;
    int nv = (VOCAB - pre) >> 2;
    const fx4* xv = (const fx4*)(x + pre);
    const fx4* pv = (const fx4*)(pd + pre);
    int per = (nv + SEG - 1) / SEG;
    int s0 = seg * per;
    int s1 = s0 + per; if (s1 > nv) s1 = nv;
    for (int i = s0 + tid; i < s1; i += 256) {
      fx4 qx = ntload4(xv + i);
      fx4 qp = ntload4(pv + i);
      int v = pre + 4 * i;
      proc(qx.x, qp.x, v);
      proc(qx.y, qp.y, v + 1);
      proc(qx.z, qp.z, v + 2);
      proc(qx.w, qp.w, v + 3);
    }
    if (seg == 0) {
      if (tid < pre) proc(x[tid], pd[tid], tid);
    }
    if (seg == SEG - 1) {
      for (int v = pre + 4 * nv + tid; v < VOCAB; v += 256) proc(x[v], pd[v], v);
    }

    __shared__ unsigned long long sp[256];
    __shared__ int sa[256];
    sp[tid] = pack_si(bc, ic); sa[tid] = any;
    __syncthreads();
    for (int st = 128; st > 0; st >>= 1) {
      if (tid < st) {
        if (sp[tid + st] > sp[tid]) sp[tid] = sp[tid + st];
        sa[tid] |= sa[tid + st];
      }
      __syncthreads();
    }
    if (tid == 0) { rec_pc_part[r] = sp[0]; rec_any_part[r] = sa[0]; }
    __syncthreads();
    sp[tid] = pack_si(bp, ip);
    __syncthreads();
    for (int st = 128; st > 0; st >>= 1) {
      if (tid < st) { if (sp[tid + st] > sp[tid]) sp[tid] = sp[tid + st]; }
      __syncthreads();
    }
    if (tid == 0) rec_pp_part[r] = sp[0];
  }
}

// ---- Kernel 3: reduce partials + assemble [bs, k+1] output (one thread per b)
__global__ void k_final(const int* __restrict__ dtok,
                        const int* __restrict__ acc_flag,
                        const unsigned long long* __restrict__ bon_part,
                        const unsigned long long* __restrict__ rec_pc_part,
                        const unsigned long long* __restrict__ rec_pp_part,
                        const int* __restrict__ rec_any_part,
                        int* __restrict__ out) {
  int b = blockIdx.x * blockDim.x + threadIdx.x;
  if (b >= BSZ) return;
  int n = nacc_flags(acc_flag, b);
  int tok_final;
  if (n == KD) {
    unsigned long long m = 0;
#pragma unroll
    for (int s = 0; s < SEG; s++) {
      unsigned long long v = bon_part[b * SEG + s];
      if (v > m) m = v;
    }
    tok_final = unpack_idx(m);
  } else {
    unsigned long long mc = 0, mp = 0; int any = 0;
#pragma unroll
    for (int s = 0; s < SEG; s++) {
      int idx = b * SEG + s;
      unsigned long long vc = rec_pc_part[idx];
      unsigned long long vp = rec_pp_part[idx];
      if (vc > mc) mc = vc;
      if (vp > mp) mp = vp;
      any |= rec_any_part[idx];
    }
    tok_final = unpack_idx(any ? mc : mp);
  }
#pragma unroll
  for (int p = 0; p <= KD; p++) {
    int val;
    if (p < n)       val = dtok[b * KD + p];
    else if (p == n) val = tok_final;
    else             val = -1;
    out[b * (KD + 1) + p] = val;
  }
}

extern "C" void kernel_launch(void* const* d_in, const int* in_sizes, int n_in,
                              void* d_out, int out_size, void* d_ws, size_t ws_size,
                              hipStream_t stream) {
  const int*   dtok   = (const int*)  d_in[0];
  const float* logits = (const float*)d_in[1];
  const float* temps  = (const float*)d_in[2];
  const float* dprobs = (const float*)d_in[3];
  int* out = (int*)d_out;

  // workspace layout — every slot that is read is unconditionally written
  // earlier in the same iteration, so NO memset is needed.
  float* row_max  = (float*)d_ws;                                    // [NDRAFT]
  float* row_sum  = row_max + NDRAFT;                                // [NDRAFT]
  int*   acc_flag = (int*)(row_sum + NDRAFT);                        // [NDRAFT]
  unsigned long long* bon_part    = (unsigned long long*)(acc_flag + NDRAFT); // [BSZ*SEG]
  unsigned long long* rec_pc_part = bon_part + BSZ * SEG;            // [BSZ*SEG]
  unsigned long long* rec_pp_part = rec_pc_part + BSZ * SEG;         // [BSZ*SEG]
  int*   rec_any_part = (int*)(rec_pp_part + BSZ * SEG);             // [BSZ*SEG]

  // nkey = key(42); split(nkey,3): subkey_i = threefry(key, (0,i))
  uint32_t ku0, ku1, kr0, kr1, kb0, kb1;
  threefry2x32(0u, 42u, 0u, 0u, ku0, ku1);   // ku       (accept uniforms)
  threefry2x32(0u, 42u, 0u, 1u, kr0, kr1);   // kg_rec   (recovery gumbel)
  threefry2x32(0u, 42u, 0u, 2u, kb0, kb1);   // kg_bonus (bonus gumbel)

  k_stats<<<NDRAFT, 256, 0, stream>>>(
      logits, temps, dtok, dprobs, row_max, row_sum, acc_flag, ku0, ku1);
  k_bonus_recover<<<2 * BSZ * SEG, 256, 0, stream>>>(
      logits, temps, dprobs, row_max, row_sum, acc_flag,
      bon_part, rec_pc_part, rec_pp_part, rec_any_part,
      kb0, kb1, kr0, kr1);
  k_final<<<1, BSZ, 0, stream>>>(
      dtok, acc_flag, bon_part, rec_pc_part, rec_pp_part, rec_any_part, out);
}